// Round 1
// baseline (252.447 us; speedup 1.0000x reference)
//
#include <hip/hip_runtime.h>

#define H 512
#define W 512
#define HW (H * W)
#define T_TOTAL 128
#define DECAY 0.8f

// ---------------------------------------------------------------------------
// Kernel A: per-pixel double-EMA scan over a time chunk.
//   p[t+1] = 0.8 p[t] + x[t]
//   r[t+1] = 0.8 r[t] + p[t]
// Writes R[t] = r-state ENTERING step t (out[t] = conv(R[t])).
// state = [p plane][r plane] in workspace; chunk 0 resets it (deterministic).
// ---------------------------------------------------------------------------
__global__ __launch_bounds__(256) void scan_chunk(
    const float* __restrict__ x, float* __restrict__ Rbuf,
    float* __restrict__ state, int t0, int tc)
{
    int pix = blockIdx.x * 256 + threadIdx.x;
    float p, r;
    if (t0 == 0) {
        p = 0.f; r = 0.f;
    } else {
        p = state[pix];
        r = state[HW + pix];
    }
    const float* xp = x + (size_t)t0 * HW + pix;
    float* rp = Rbuf + pix;
    for (int t = 0; t < tc; ++t) {
        rp[(size_t)t * HW] = r;
        float xv = xp[(size_t)t * HW];
        float rn = __builtin_fmaf(DECAY, r, p);   // uses old p
        p = __builtin_fmaf(DECAY, p, xv);
        r = rn;
    }
    state[pix] = p;
    state[HW + pix] = r;
}

// ---------------------------------------------------------------------------
// Kernel B: batched 9x9 conv, zero pad 4. One block = 64x32 output tile of one
// time plane. 256 threads; each thread computes an 8-wide run (col = tid&7,
// row = tid>>3). LDS tile row stride 76 words -> the 4x ds_read_b128 window
// loads spread evenly over all 32 banks (8 words/bank, optimal for b128).
// ---------------------------------------------------------------------------
#define TILE_X 64
#define TILE_Y 32
#define HALO 4
#define LW 72      // loaded width  (64 + 8)
#define LH 40      // loaded height (32 + 8)
#define LSTRIDE 76 // padded row stride (words)

__global__ __launch_bounds__(256) void conv_chunk(
    const float* __restrict__ Rbuf, const float* __restrict__ w,
    float* __restrict__ out, int t0)
{
    __shared__ float tile[LH][LSTRIDE];
    __shared__ float wsm[81];

    int tid = threadIdx.x;
    int tileX = blockIdx.x;   // 0..7
    int tileY = blockIdx.y;   // 0..15
    int tt = blockIdx.z;      // chunk-local time index
    const float* Rp = Rbuf + (size_t)tt * HW;

    if (tid < 81) wsm[tid] = w[tid];

    int x0 = tileX * TILE_X - HALO;
    int y0 = tileY * TILE_Y - HALO;
    for (int e = tid; e < LH * LW; e += 256) {
        int ly = e / LW;
        int lx = e - ly * LW;
        int gx = x0 + lx;
        int gy = y0 + ly;
        float v = 0.f;
        if ((unsigned)gx < W && (unsigned)gy < H)
            v = Rp[gy * W + gx];
        tile[ly][lx] = v;
    }
    __syncthreads();

    int col = tid & 7;    // 0..7  -> 8-wide output run at x = col*8
    int row = tid >> 3;   // 0..31 -> output row within tile

    float acc[8] = {0.f, 0.f, 0.f, 0.f, 0.f, 0.f, 0.f, 0.f};
    #pragma unroll
    for (int ky = 0; ky < 9; ++ky) {
        float win[16];
        const float* tp = &tile[row + ky][col * 8];
        #pragma unroll
        for (int j = 0; j < 16; ++j) win[j] = tp[j];  // 4x ds_read_b128
        #pragma unroll
        for (int kx = 0; kx < 9; ++kx) {
            float wv = wsm[ky * 9 + kx];
            #pragma unroll
            for (int j = 0; j < 8; ++j)
                acc[j] = __builtin_fmaf(wv, win[kx + j], acc[j]);
        }
    }

    int ox = tileX * TILE_X + col * 8;
    int oy = tileY * TILE_Y + row;
    float4* op = (float4*)(out + (size_t)(t0 + tt) * HW + (size_t)oy * W + ox);
    op[0] = make_float4(acc[0], acc[1], acc[2], acc[3]);
    op[1] = make_float4(acc[4], acc[5], acc[6], acc[7]);
}

// ---------------------------------------------------------------------------
extern "C" void kernel_launch(void* const* d_in, const int* in_sizes, int n_in,
                              void* d_out, int out_size, void* d_ws, size_t ws_size,
                              hipStream_t stream) {
    const float* x = (const float*)d_in[0];   // [128,1,512,512]
    const float* w = (const float*)d_in[1];   // [1,1,9,9]
    float* out = (float*)d_out;               // [128,1,512,512]

    float* state = (float*)d_ws;              // 2 planes: p, r
    float* Rbuf = state + 2 * HW;

    size_t plane_bytes = (size_t)HW * sizeof(float);
    // Chunk the time axis so the R intermediate stays cache-resident between
    // the scan and conv kernels. Prefer 32 planes (32 MB), adapt to ws_size.
    int maxTc = 1;
    if (ws_size > 3 * plane_bytes)
        maxTc = (int)((ws_size - 2 * plane_bytes) / plane_bytes);
    int Tc = 32;
    if (Tc > maxTc) Tc = maxTc;
    if (Tc > T_TOTAL) Tc = T_TOTAL;
    if (Tc < 1) Tc = 1;

    for (int t0 = 0; t0 < T_TOTAL; t0 += Tc) {
        int tc = T_TOTAL - t0;
        if (tc > Tc) tc = Tc;
        scan_chunk<<<dim3(HW / 256), 256, 0, stream>>>(x, Rbuf, state, t0, tc);
        conv_chunk<<<dim3(W / TILE_X, H / TILE_Y, tc), 256, 0, stream>>>(Rbuf, w, out, t0);
    }
}